// Round 1
// baseline (289.690 us; speedup 1.0000x reference)
//
#include <hip/hip_runtime.h>

// NonLocalBlock fp32, MI355X. Sizes fixed by the reference.
#define BATCH 2
#define CIN   64
#define COUT  32
#define HW    6400           // 80*80
#define NROW  HW             // attention rows per batch
#define PB    (COUT*HW)      // 204800 floats per batch for conv outputs (theta/phi/g)
#define XB    (CIN*HW)       // 409600 floats per batch for x / z
#define KT    64             // key sub-tile staged in LDS

// ---------------------------------------------------------------------------
// Kernel 1: three 1x1 convs.  out[b][o][s] = sum_c w[o][c] * x[b][c][s] + bias[o]
// Natural [b][o][s] layout == the "raw reshape" [b][n][c] view (n*32+c flat).
// grid (25, 3, B), block 256: blockIdx.y selects which weight matrix.
// ---------------------------------------------------------------------------
__global__ __launch_bounds__(256) void conv3_kernel(
    const float* __restrict__ x,
    const float* __restrict__ w0, const float* __restrict__ bb0,   // theta -> T
    const float* __restrict__ w1, const float* __restrict__ bb1,   // phi   -> P
    const float* __restrict__ w2, const float* __restrict__ bb2,   // g     -> G
    float* __restrict__ T, float* __restrict__ P, float* __restrict__ G) {
  const int which = blockIdx.y;
  const float* w  = (which == 0) ? w0 : (which == 1) ? w1 : w2;
  const float* bv = (which == 0) ? bb0 : (which == 1) ? bb1 : bb2;
  float* out      = (which == 0) ? T : (which == 1) ? P : G;
  const int b = blockIdx.z;
  const int s = blockIdx.x * 256 + threadIdx.x;   // 25*256 == 6400, no bounds check

  __shared__ float ws[COUT * CIN];                // 8 KiB
  for (int i = threadIdx.x; i < COUT * CIN; i += 256) ws[i] = w[i];
  __syncthreads();

  float xr[CIN];
#pragma unroll
  for (int c = 0; c < CIN; ++c) xr[c] = x[b * XB + c * HW + s];   // coalesced

  for (int o = 0; o < COUT; ++o) {
    const float4* wr = (const float4*)&ws[o * CIN];
    float acc = 0.f;
#pragma unroll
    for (int q = 0; q < CIN / 4; ++q) {
      float4 wv = wr[q];                          // LDS broadcast, conflict-free
      acc += wv.x * xr[4*q] + wv.y * xr[4*q+1] + wv.z * xr[4*q+2] + wv.w * xr[4*q+3];
    }
    out[b * PB + o * HW + s] = acc + bv[o];       // coalesced
  }
}

// ---------------------------------------------------------------------------
// Kernel 2: fused attention partial.  One query row per thread; keys split
// across blockIdx.y chunks (split-K is exact: no max-subtraction in reference,
// so partial sum(exp) / sum(exp*g) combine linearly).
// grid (25, nchunk, B), block 256.
// ---------------------------------------------------------------------------
__global__ __launch_bounds__(256) void attn_partial(
    const float* __restrict__ T, const float* __restrict__ P,
    const float* __restrict__ G,
    float* __restrict__ part_y,   // [nchunk][B][N][32]
    float* __restrict__ part_d,   // [nchunk][B][N]
    int kchunk) {
  const int b = blockIdx.z;
  const int n = blockIdx.x * 256 + threadIdx.x;
  const int kstart = blockIdx.y * kchunk;

  __shared__ float Pl[KT][32];    // 8 KiB
  __shared__ float Gl[KT][32];    // 8 KiB

  // theta row for this thread: 32 contiguous floats (raw-reshape view)
  float4 t4[8];
  {
    const float4* tp = (const float4*)&T[(size_t)b * PB + (size_t)n * 32];
#pragma unroll
    for (int q = 0; q < 8; ++q) t4[q] = tp[q];
  }

  float acc[32] = {};   // running sum(exp * g)
  float denom = 0.f;    // running sum(exp)

  for (int k0 = kstart; k0 < kstart + kchunk; k0 += KT) {
    __syncthreads();    // previous tile consumed
    {
      // cooperative stage: KT*32 floats each = 512 float4; 2 per thread
      const float4* Psrc = (const float4*)&P[(size_t)b * PB + (size_t)k0 * 32];
      const float4* Gsrc = (const float4*)&G[(size_t)b * PB + (size_t)k0 * 32];
      float4* Pd = (float4*)&Pl[0][0];
      float4* Gd = (float4*)&Gl[0][0];
      Pd[threadIdx.x]       = Psrc[threadIdx.x];
      Pd[threadIdx.x + 256] = Psrc[threadIdx.x + 256];
      Gd[threadIdx.x]       = Gsrc[threadIdx.x];
      Gd[threadIdx.x + 256] = Gsrc[threadIdx.x + 256];
    }
    __syncthreads();

#pragma unroll 4
    for (int m = 0; m < KT; ++m) {
      const float4* Pm = (const float4*)&Pl[m][0];   // broadcast reads
      float sdot = 0.f;
#pragma unroll
      for (int q = 0; q < 8; ++q) {
        float4 pv = Pm[q];
        sdot += t4[q].x * pv.x + t4[q].y * pv.y + t4[q].z * pv.z + t4[q].w * pv.w;
      }
      const float e = __expf(sdot);                  // scores are O(0.15), safe
      denom += e;
      const float4* Gm = (const float4*)&Gl[m][0];
#pragma unroll
      for (int q = 0; q < 8; ++q) {
        float4 gv = Gm[q];
        acc[4*q+0] += e * gv.x; acc[4*q+1] += e * gv.y;
        acc[4*q+2] += e * gv.z; acc[4*q+3] += e * gv.w;
      }
    }
  }

  const size_t base = ((size_t)blockIdx.y * BATCH + b) * NROW + n;
  part_d[base] = denom;
  float4* py = (float4*)&part_y[base * 32];
#pragma unroll
  for (int q = 0; q < 8; ++q)
    py[q] = make_float4(acc[4*q+0], acc[4*q+1], acc[4*q+2], acc[4*q+3]);
}

// ---------------------------------------------------------------------------
// Kernel 3: deterministic chunk reduction + normalize.
// y[b][n][c] = sum_ch part_y / sum_ch part_d.  y stored flat [b][n*32+c],
// which the final conv reads as the [b][o][s] view (raw reshape again).
// ---------------------------------------------------------------------------
__global__ __launch_bounds__(256) void reduce_kernel(
    const float* __restrict__ part_y, const float* __restrict__ part_d,
    float* __restrict__ y, int nchunk) {
  const int idx = blockIdx.x * 256 + threadIdx.x;   // over B*N*32 = 409600
  const int bn = idx >> 5;
  const int j  = idx & 31;
  float d = 0.f, a = 0.f;
  for (int ch = 0; ch < nchunk; ++ch) {
    d += part_d[(size_t)ch * (BATCH * NROW) + bn];                  // broadcast
    a += part_y[((size_t)ch * (BATCH * NROW) + bn) * 32 + j];       // coalesced
  }
  y[idx] = a / d;
}

// ---------------------------------------------------------------------------
// Kernel 4: final 1x1 conv.  z[b][i][s] = sum_o w_y[i][o] * yview[b][o][s] + b_y[i]
// where yview[b][o][s] = y_flat[b][o*HW + s].
// grid (25, B), block 256.
// ---------------------------------------------------------------------------
__global__ __launch_bounds__(256) void conv_out_kernel(
    const float* __restrict__ y, const float* __restrict__ wy,
    const float* __restrict__ by, float* __restrict__ z) {
  const int b = blockIdx.y;
  const int s = blockIdx.x * 256 + threadIdx.x;

  __shared__ float ws[CIN * COUT];   // 8 KiB, w_y is [CIN][COUT] row-major
  for (int i = threadIdx.x; i < CIN * COUT; i += 256) ws[i] = wy[i];
  __syncthreads();

  float yr[COUT];
#pragma unroll
  for (int o = 0; o < COUT; ++o) yr[o] = y[(size_t)b * PB + o * HW + s];

  for (int i = 0; i < CIN; ++i) {
    const float4* wr = (const float4*)&ws[i * COUT];
    float acc = 0.f;
#pragma unroll
    for (int q = 0; q < COUT / 4; ++q) {
      float4 wv = wr[q];
      acc += wv.x * yr[4*q] + wv.y * yr[4*q+1] + wv.z * yr[4*q+2] + wv.w * yr[4*q+3];
    }
    z[(size_t)b * XB + i * HW + s] = acc + by[i];
  }
}

// ---------------------------------------------------------------------------
extern "C" void kernel_launch(void* const* d_in, const int* in_sizes, int n_in,
                              void* d_out, int out_size, void* d_ws, size_t ws_size,
                              hipStream_t stream) {
  const float* x       = (const float*)d_in[0];
  const float* w_g     = (const float*)d_in[1];
  const float* b_g     = (const float*)d_in[2];
  const float* w_phi   = (const float*)d_in[3];
  const float* b_phi   = (const float*)d_in[4];
  const float* w_theta = (const float*)d_in[5];
  const float* b_theta = (const float*)d_in[6];
  const float* w_y     = (const float*)d_in[7];
  const float* b_y     = (const float*)d_in[8];
  float* z  = (float*)d_out;
  float* ws = (float*)d_ws;

  float* T = ws;                       // [B][PB]
  float* P = T + (size_t)BATCH * PB;
  float* G = P + (size_t)BATCH * PB;
  float* Y = G + (size_t)BATCH * PB;   // [B][PB]
  float* part = Y + (size_t)BATCH * PB;
  const size_t fixed_floats = (size_t)4 * BATCH * PB;

  // pick the largest key-split that fits the workspace (all divide 6400 into
  // multiples of KT=64, so the attention inner tile is always full)
  const int cand[6] = {20, 10, 5, 4, 2, 1};
  int nchunk = 1;
  for (int i = 0; i < 6; ++i) {
    size_t need = (fixed_floats + (size_t)cand[i] * BATCH * NROW * 33) * sizeof(float);
    if (need <= ws_size) { nchunk = cand[i]; break; }
  }
  float* part_y = part;
  float* part_d = part + (size_t)nchunk * BATCH * NROW * 32;
  const int kchunk = NROW / nchunk;

  conv3_kernel<<<dim3(25, 3, BATCH), 256, 0, stream>>>(
      x, w_theta, b_theta, w_phi, b_phi, w_g, b_g, T, P, G);
  attn_partial<<<dim3(25, nchunk, BATCH), 256, 0, stream>>>(
      T, P, G, part_y, part_d, kchunk);
  reduce_kernel<<<dim3((BATCH * NROW * 32) / 256), 256, 0, stream>>>(
      part_y, part_d, Y, nchunk);
  conv_out_kernel<<<dim3(25, BATCH), 256, 0, stream>>>(Y, w_y, b_y, z);
}

// Round 2
// 270.356 us; speedup vs baseline: 1.0715x; 1.0715x over previous
//
#include <hip/hip_runtime.h>

// NonLocalBlock fp32, MI355X. Sizes fixed by the reference.
#define BATCH 2
#define CIN   64
#define COUT  32
#define HW    6400           // 80*80
#define NROW  HW             // attention rows per batch
#define PB    (COUT*HW)      // 204800 floats per batch for conv outputs (theta/phi/g)
#define XB    (CIN*HW)       // 409600 floats per batch for x / z
#define KT    64             // key sub-tile staged in LDS

// ---------------------------------------------------------------------------
// Kernel 1: three 1x1 convs.  out[b][o][s] = sum_c w[o][c] * x[b][c][s] + bias[o]
// ---------------------------------------------------------------------------
__global__ __launch_bounds__(256) void conv3_kernel(
    const float* __restrict__ x,
    const float* __restrict__ w0, const float* __restrict__ bb0,   // theta -> T
    const float* __restrict__ w1, const float* __restrict__ bb1,   // phi   -> P
    const float* __restrict__ w2, const float* __restrict__ bb2,   // g     -> G
    float* __restrict__ T, float* __restrict__ P, float* __restrict__ G) {
  const int which = blockIdx.y;
  const float* w  = (which == 0) ? w0 : (which == 1) ? w1 : w2;
  const float* bv = (which == 0) ? bb0 : (which == 1) ? bb1 : bb2;
  float* out      = (which == 0) ? T : (which == 1) ? P : G;
  const int b = blockIdx.z;
  const int s = blockIdx.x * 256 + threadIdx.x;   // 25*256 == 6400

  __shared__ float ws[COUT * CIN];                // 8 KiB
  for (int i = threadIdx.x; i < COUT * CIN; i += 256) ws[i] = w[i];
  __syncthreads();

  float xr[CIN];
#pragma unroll
  for (int c = 0; c < CIN; ++c) xr[c] = x[b * XB + c * HW + s];   // coalesced

  for (int o = 0; o < COUT; ++o) {
    const float4* wr = (const float4*)&ws[o * CIN];
    float acc = 0.f;
#pragma unroll
    for (int q = 0; q < CIN / 4; ++q) {
      float4 wv = wr[q];
      acc += wv.x * xr[4*q] + wv.y * xr[4*q+1] + wv.z * xr[4*q+2] + wv.w * xr[4*q+3];
    }
    out[b * PB + o * HW + s] = acc + bv[o];       // coalesced
  }
}

// ---------------------------------------------------------------------------
// Kernel 2: fused attention partial.  One query row per thread; keys split
// across blockIdx.y chunks (exact: no max-subtraction -> partials combine
// linearly).  grid (25, nchunk, B), block 256.
// Round-2 changes: (a) 4-way independent partial sums for the QK dot product
// (breaks the 32-long serial FMA chain), (b) caller now splits keys finer
// (nchunk=50) so the grid offers ~39 waves/CU instead of 15.6.
// ---------------------------------------------------------------------------
__global__ __launch_bounds__(256) void attn_partial(
    const float* __restrict__ T, const float* __restrict__ P,
    const float* __restrict__ G,
    float* __restrict__ part_y,   // [nchunk][B][N][32]
    float* __restrict__ part_d,   // [nchunk][B][N]
    int kchunk) {
  const int b = blockIdx.z;
  const int n = blockIdx.x * 256 + threadIdx.x;
  const int kstart = blockIdx.y * kchunk;

  __shared__ float Pl[KT * 32];    // 8 KiB
  __shared__ float Gl[KT * 32];    // 8 KiB

  // theta row for this thread: 32 contiguous floats (raw-reshape view)
  float4 t4[8];
  {
    const float4* tp = (const float4*)&T[(size_t)b * PB + (size_t)n * 32];
#pragma unroll
    for (int q = 0; q < 8; ++q) t4[q] = tp[q];
  }

  float acc[32] = {};   // running sum(exp * g)
  float denom = 0.f;    // running sum(exp)

  for (int k0 = kstart; k0 < kstart + kchunk; k0 += KT) {
    __syncthreads();    // previous tile consumed
    {
      // cooperative stage: KT*32 floats each = 512 float4; 2 per thread
      const float4* Psrc = (const float4*)&P[(size_t)b * PB + (size_t)k0 * 32];
      const float4* Gsrc = (const float4*)&G[(size_t)b * PB + (size_t)k0 * 32];
      float4* Pd = (float4*)Pl;
      float4* Gd = (float4*)Gl;
      Pd[threadIdx.x]       = Psrc[threadIdx.x];
      Pd[threadIdx.x + 256] = Psrc[threadIdx.x + 256];
      Gd[threadIdx.x]       = Gsrc[threadIdx.x];
      Gd[threadIdx.x + 256] = Gsrc[threadIdx.x + 256];
    }
    __syncthreads();

#pragma unroll 2
    for (int m = 0; m < KT; ++m) {
      const float4* Pm = (const float4*)&Pl[m * 32];   // broadcast reads
      float s0 = 0.f, s1 = 0.f, s2 = 0.f, s3 = 0.f;    // 4 independent chains
#pragma unroll
      for (int q = 0; q < 8; q += 4) {
        float4 p0 = Pm[q], p1 = Pm[q+1], p2 = Pm[q+2], p3 = Pm[q+3];
        s0 += t4[q  ].x * p0.x + t4[q  ].y * p0.y + t4[q  ].z * p0.z + t4[q  ].w * p0.w;
        s1 += t4[q+1].x * p1.x + t4[q+1].y * p1.y + t4[q+1].z * p1.z + t4[q+1].w * p1.w;
        s2 += t4[q+2].x * p2.x + t4[q+2].y * p2.y + t4[q+2].z * p2.z + t4[q+2].w * p2.w;
        s3 += t4[q+3].x * p3.x + t4[q+3].y * p3.y + t4[q+3].z * p3.z + t4[q+3].w * p3.w;
      }
      const float e = __expf((s0 + s1) + (s2 + s3));   // scores O(0.15), safe
      denom += e;
      const float4* Gm = (const float4*)&Gl[m * 32];
#pragma unroll
      for (int q = 0; q < 8; ++q) {
        float4 gv = Gm[q];
        acc[4*q+0] += e * gv.x; acc[4*q+1] += e * gv.y;
        acc[4*q+2] += e * gv.z; acc[4*q+3] += e * gv.w;
      }
    }
  }

  const size_t base = ((size_t)blockIdx.y * BATCH + b) * NROW + n;
  part_d[base] = denom;
  float4* py = (float4*)&part_y[base * 32];
#pragma unroll
  for (int q = 0; q < 8; ++q)
    py[q] = make_float4(acc[4*q+0], acc[4*q+1], acc[4*q+2], acc[4*q+3]);
}

// ---------------------------------------------------------------------------
// Kernel 3: deterministic chunk reduction + normalize.
// ---------------------------------------------------------------------------
__global__ __launch_bounds__(256) void reduce_kernel(
    const float* __restrict__ part_y, const float* __restrict__ part_d,
    float* __restrict__ y, int nchunk) {
  const int idx = blockIdx.x * 256 + threadIdx.x;   // over B*N*32 = 409600
  const int bn = idx >> 5;
  const int j  = idx & 31;
  float d = 0.f, a = 0.f;
  for (int ch = 0; ch < nchunk; ++ch) {
    d += part_d[(size_t)ch * (BATCH * NROW) + bn];                  // broadcast
    a += part_y[((size_t)ch * (BATCH * NROW) + bn) * 32 + j];       // coalesced
  }
  y[idx] = a / d;
}

// ---------------------------------------------------------------------------
// Kernel 4: final 1x1 conv.
// ---------------------------------------------------------------------------
__global__ __launch_bounds__(256) void conv_out_kernel(
    const float* __restrict__ y, const float* __restrict__ wy,
    const float* __restrict__ by, float* __restrict__ z) {
  const int b = blockIdx.y;
  const int s = blockIdx.x * 256 + threadIdx.x;

  __shared__ float ws[CIN * COUT];   // 8 KiB, w_y is [CIN][COUT] row-major
  for (int i = threadIdx.x; i < CIN * COUT; i += 256) ws[i] = wy[i];
  __syncthreads();

  float yr[COUT];
#pragma unroll
  for (int o = 0; o < COUT; ++o) yr[o] = y[(size_t)b * PB + o * HW + s];

  for (int i = 0; i < CIN; ++i) {
    const float4* wr = (const float4*)&ws[i * COUT];
    float acc = 0.f;
#pragma unroll
    for (int q = 0; q < COUT / 4; ++q) {
      float4 wv = wr[q];
      acc += wv.x * yr[4*q] + wv.y * yr[4*q+1] + wv.z * yr[4*q+2] + wv.w * yr[4*q+3];
    }
    z[(size_t)b * XB + i * HW + s] = acc + by[i];
  }
}

// ---------------------------------------------------------------------------
extern "C" void kernel_launch(void* const* d_in, const int* in_sizes, int n_in,
                              void* d_out, int out_size, void* d_ws, size_t ws_size,
                              hipStream_t stream) {
  const float* x       = (const float*)d_in[0];
  const float* w_g     = (const float*)d_in[1];
  const float* b_g     = (const float*)d_in[2];
  const float* w_phi   = (const float*)d_in[3];
  const float* b_phi   = (const float*)d_in[4];
  const float* w_theta = (const float*)d_in[5];
  const float* b_theta = (const float*)d_in[6];
  const float* w_y     = (const float*)d_in[7];
  const float* b_y     = (const float*)d_in[8];
  float* z  = (float*)d_out;
  float* ws = (float*)d_ws;

  float* T = ws;                       // [B][PB]
  float* P = T + (size_t)BATCH * PB;
  float* G = P + (size_t)BATCH * PB;
  float* Y = G + (size_t)BATCH * PB;   // [B][PB]
  float* part = Y + (size_t)BATCH * PB;
  const size_t fixed_floats = (size_t)4 * BATCH * PB;

  // largest key-split that fits the workspace; kchunk stays a multiple of KT=64
  const int cand[7] = {50, 25, 20, 10, 5, 2, 1};
  int nchunk = 1;
  for (int i = 0; i < 7; ++i) {
    size_t need = (fixed_floats + (size_t)cand[i] * BATCH * NROW * 33) * sizeof(float);
    if (need <= ws_size) { nchunk = cand[i]; break; }
  }
  float* part_y = part;
  float* part_d = part + (size_t)nchunk * BATCH * NROW * 32;
  const int kchunk = NROW / nchunk;

  conv3_kernel<<<dim3(25, 3, BATCH), 256, 0, stream>>>(
      x, w_theta, b_theta, w_phi, b_phi, w_g, b_g, T, P, G);
  attn_partial<<<dim3(25, nchunk, BATCH), 256, 0, stream>>>(
      T, P, G, part_y, part_d, kchunk);
  reduce_kernel<<<dim3((BATCH * NROW * 32) / 256), 256, 0, stream>>>(
      part_y, part_d, Y, nchunk);
  conv_out_kernel<<<dim3(25, BATCH), 256, 0, stream>>>(Y, w_y, b_y, z);
}

// Round 3
// 176.285 us; speedup vs baseline: 1.6433x; 1.5336x over previous
//
#include <hip/hip_runtime.h>
#include <hip/hip_bf16.h>

// NonLocalBlock fp32 -> split-bf16 MFMA, MI355X. Sizes fixed by the reference.
#define BATCH 2
#define CIN   64
#define COUT  32
#define HW    6400           // 80*80
#define PB    (COUT*HW)      // 204800 elems per batch for T/P/G (M-view 6400x32)
#define XB    (CIN*HW)       // 409600 elems per batch for x / z

typedef __attribute__((ext_vector_type(8))) short  bf16x8;  // MFMA A/B frag (4 VGPR)
typedef __attribute__((ext_vector_type(4))) float  f32x4;   // MFMA C/D frag

typedef unsigned short ushort;
typedef unsigned int   uint;

__device__ inline uint pk2(float a, float b) {
  // pack 2 floats -> 2 bf16 (RTNE), low short = a
  __hip_bfloat162 h = __float22bfloat162_rn(make_float2(a, b));
  union { __hip_bfloat162 h2; uint u; } cv; cv.h2 = h;
  return cv.u;
}
__device__ inline float up_lo(uint u) { return __uint_as_float(u << 16); }
__device__ inline float up_hi(uint u) { return __uint_as_float(u & 0xFFFF0000u); }

// ---------------------------------------------------------------------------
// Kernel 1: three 1x1 convs -> bf16 hi/lo split flat buffers.
// out_hi[f] = bf16(v), out_lo[f] = bf16(v - float(out_hi[f])), f = o*HW + s.
// The flat buffer IS the raw-reshape M-view [6400][32] (row n = 32 contiguous).
// grid (25, 3, B), block 256.
// ---------------------------------------------------------------------------
__global__ __launch_bounds__(256) void conv3_kernel(
    const float* __restrict__ x,
    const float* __restrict__ w0, const float* __restrict__ bb0,   // theta
    const float* __restrict__ w1, const float* __restrict__ bb1,   // phi
    const float* __restrict__ w2, const float* __restrict__ bb2,   // g
    ushort* __restrict__ T_hi, ushort* __restrict__ T_lo,
    ushort* __restrict__ P_hi, ushort* __restrict__ P_lo,
    ushort* __restrict__ G_hi, ushort* __restrict__ G_lo) {
  const int which = blockIdx.y;
  const float* w  = (which == 0) ? w0 : (which == 1) ? w1 : w2;
  const float* bv = (which == 0) ? bb0 : (which == 1) ? bb1 : bb2;
  ushort* ohi = (which == 0) ? T_hi : (which == 1) ? P_hi : G_hi;
  ushort* olo = (which == 0) ? T_lo : (which == 1) ? P_lo : G_lo;
  const int b = blockIdx.z;
  const int s = blockIdx.x * 256 + threadIdx.x;   // 25*256 == 6400

  __shared__ float wsm[COUT * CIN];               // 8 KiB
  for (int i = threadIdx.x; i < COUT * CIN; i += 256) wsm[i] = w[i];
  __syncthreads();

  float xr[CIN];
#pragma unroll
  for (int c = 0; c < CIN; ++c) xr[c] = x[b * XB + c * HW + s];   // coalesced

  for (int o = 0; o < COUT; ++o) {
    const float4* wr = (const float4*)&wsm[o * CIN];
    float acc = 0.f;
#pragma unroll
    for (int q = 0; q < CIN / 4; ++q) {
      float4 wv = wr[q];
      acc += wv.x * xr[4*q] + wv.y * xr[4*q+1] + wv.z * xr[4*q+2] + wv.w * xr[4*q+3];
    }
    acc += bv[o];
    const int f = b * PB + o * HW + s;
    uint hb = pk2(acc, 0.f) & 0xFFFFu;            // bf16(acc) bits
    float hf = __uint_as_float(hb << 16);
    uint lb = pk2(acc - hf, 0.f) & 0xFFFFu;
    ohi[f] = (ushort)hb;
    olo[f] = (ushort)lb;
  }
}

// ---------------------------------------------------------------------------
// Kernel 2: permuted transpose of G: Gt[b][c][n'] = G_M[(n'&~31)+sigma(n'&31)][c]
// sigma(p) = 4*(p>>3) + (p&3) + 16*((p>>2)&1)  (PV slot->key map, bijective /32)
// grid (100, B), block 256; thread handles 8 consecutive n' for hi and lo.
// Scattered 2B reads served by L2 (G fits easily); 16B coalesced writes.
// ---------------------------------------------------------------------------
__global__ __launch_bounds__(256) void transpose_g_kernel(
    const ushort* __restrict__ G_hi, const ushort* __restrict__ G_lo,
    ushort* __restrict__ Gt_hi, ushort* __restrict__ Gt_lo) {
  const int b = blockIdx.y;
  const int o = blockIdx.x * 256 + threadIdx.x;   // 0..25600
  const int c   = o / 800;
  const int n0  = (o % 800) * 8;

  ushort vh[8], vl[8];
#pragma unroll
  for (int j = 0; j < 8; ++j) {
    int np = n0 + j;
    int p  = np & 31;
    int ns = (np & ~31) + 4*(p>>3) + (p&3) + 16*((p>>2)&1);
    int src = b * PB + ns * 32 + c;
    vh[j] = G_hi[src];
    vl[j] = G_lo[src];
  }
  const int dst = b * PB + c * HW + n0;
#pragma unroll
  for (int j = 0; j < 8; ++j) { Gt_hi[dst + j] = vh[j]; Gt_lo[dst + j] = vl[j]; }
}

// ---------------------------------------------------------------------------
// Kernel 3: fused attention, split-bf16 MFMA.
// grid (200, B) x 512 threads (8 waves). Block owns 32 queries.
// wave w: wq = w>>2 (q-subtile of 16), wk = w&3 (key split, k-groups wk::4).
// Per 32-key group:
//   S^T = mfma_16x16x32(P_frag, T_frag)  x2 subtiles x3 splits
//     D layout: col=lane&15=query, row=4g+r=key   (guide m89, verified)
//   e = __expf(S); hi/lo split; packed A-frag slots = [eaT0 r0..3, eaT1 r0..3]
//   Y += mfma_16x16x32(p_frag, gt_frag)  x2 chan-tiles x3 splits
//     (Gt stored key-permuted so B-frag slot k matches A-frag slot k)
// Block-local LDS combine across wk + normalize -> Y f32 flat (M-view).
// ---------------------------------------------------------------------------
__global__ __launch_bounds__(512, 4) void attn_kernel(
    const ushort* __restrict__ T_hi, const ushort* __restrict__ T_lo,
    const ushort* __restrict__ P_hi, const ushort* __restrict__ P_lo,
    const ushort* __restrict__ Gt_hi, const ushort* __restrict__ Gt_lo,
    float* __restrict__ Y) {
  const int b     = blockIdx.y;
  const int q_blk = blockIdx.x;          // 0..199
  const int tid   = threadIdx.x;
  const int w     = tid >> 6;            // wave 0..7
  const int lane  = tid & 63;
  const int wq    = w >> 2;              // 0..1
  const int wk    = w & 3;               // 0..3
  const int l15   = lane & 15;
  const int g     = lane >> 4;           // 0..3

  __shared__ float ylds[8][16][33];      // 16.9 KiB (pad kills bank conflicts)
  __shared__ float dlds[8][16];

  // T fragment (B-operand of QK): row q, chans g*8..+8, loaded once
  const int qrow = q_blk * 32 + wq * 16 + l15;
  const bf16x8 t_hi = *(const bf16x8*)&T_hi[b * PB + qrow * 32 + g * 8];
  const bf16x8 t_lo = *(const bf16x8*)&T_lo[b * PB + qrow * 32 + g * 8];

  f32x4 acc0 = {0.f, 0.f, 0.f, 0.f};     // chans 0..15  (query rows 4g+r)
  f32x4 acc1 = {0.f, 0.f, 0.f, 0.f};     // chans 16..31
  float denom = 0.f;

  for (int kt = wk; kt < 200; kt += 4) {
    const int m0 = kt * 32;

    // P fragments (A-operand): rows m0+l15 and m0+16+l15, chans g*8..+8
    const int pa = b * PB + (m0 + l15) * 32 + g * 8;
    const bf16x8 pa_hi = *(const bf16x8*)&P_hi[pa];
    const bf16x8 pa_lo = *(const bf16x8*)&P_lo[pa];
    const bf16x8 pb_hi = *(const bf16x8*)&P_hi[pa + 512];   // +16 rows
    const bf16x8 pb_lo = *(const bf16x8*)&P_lo[pa + 512];

    // Gt fragments (B-operand of PV): chan rows ct*16+l15, perm-keys m0+g*8
    const int ga = b * PB + l15 * HW + m0 + g * 8;
    const bf16x8 g0_hi = *(const bf16x8*)&Gt_hi[ga];
    const bf16x8 g0_lo = *(const bf16x8*)&Gt_lo[ga];
    const bf16x8 g1_hi = *(const bf16x8*)&Gt_hi[ga + 16 * HW];
    const bf16x8 g1_lo = *(const bf16x8*)&Gt_lo[ga + 16 * HW];

    // QK^T (swapped): S^T = P . T^T, split products hh + hl + lh
    f32x4 sa = {0.f, 0.f, 0.f, 0.f};
    f32x4 sb = {0.f, 0.f, 0.f, 0.f};
    sa = __builtin_amdgcn_mfma_f32_16x16x32_bf16(pa_hi, t_hi, sa, 0, 0, 0);
    sa = __builtin_amdgcn_mfma_f32_16x16x32_bf16(pa_hi, t_lo, sa, 0, 0, 0);
    sa = __builtin_amdgcn_mfma_f32_16x16x32_bf16(pa_lo, t_hi, sa, 0, 0, 0);
    sb = __builtin_amdgcn_mfma_f32_16x16x32_bf16(pb_hi, t_hi, sb, 0, 0, 0);
    sb = __builtin_amdgcn_mfma_f32_16x16x32_bf16(pb_hi, t_lo, sb, 0, 0, 0);
    sb = __builtin_amdgcn_mfma_f32_16x16x32_bf16(pb_lo, t_hi, sb, 0, 0, 0);

    // exp (scores ~O(0.15), no overflow; reference uses raw exp)
    const float ea0 = __expf(sa[0]), ea1 = __expf(sa[1]);
    const float ea2 = __expf(sa[2]), ea3 = __expf(sa[3]);
    const float eb0 = __expf(sb[0]), eb1 = __expf(sb[1]);
    const float eb2 = __expf(sb[2]), eb3 = __expf(sb[3]);
    denom += ((ea0 + ea1) + (ea2 + ea3)) + ((eb0 + eb1) + (eb2 + eb3));

    // split exp'd P into hi/lo bf16x8 A-frags; slot order [ea r0..3, eb r0..3]
    union { uint u[4]; bf16x8 v; } ph, pl;
    ph.u[0] = pk2(ea0, ea1); ph.u[1] = pk2(ea2, ea3);
    ph.u[2] = pk2(eb0, eb1); ph.u[3] = pk2(eb2, eb3);
    pl.u[0] = pk2(ea0 - up_lo(ph.u[0]), ea1 - up_hi(ph.u[0]));
    pl.u[1] = pk2(ea2 - up_lo(ph.u[1]), ea3 - up_hi(ph.u[1]));
    pl.u[2] = pk2(eb0 - up_lo(ph.u[2]), eb1 - up_hi(ph.u[2]));
    pl.u[3] = pk2(eb2 - up_lo(ph.u[3]), eb3 - up_hi(ph.u[3]));

    // PV: Y += P_exp . G
    acc0 = __builtin_amdgcn_mfma_f32_16x16x32_bf16(ph.v, g0_hi, acc0, 0, 0, 0);
    acc0 = __builtin_amdgcn_mfma_f32_16x16x32_bf16(ph.v, g0_lo, acc0, 0, 0, 0);
    acc0 = __builtin_amdgcn_mfma_f32_16x16x32_bf16(pl.v, g0_hi, acc0, 0, 0, 0);
    acc1 = __builtin_amdgcn_mfma_f32_16x16x32_bf16(ph.v, g1_hi, acc1, 0, 0, 0);
    acc1 = __builtin_amdgcn_mfma_f32_16x16x32_bf16(ph.v, g1_lo, acc1, 0, 0, 0);
    acc1 = __builtin_amdgcn_mfma_f32_16x16x32_bf16(pl.v, g1_hi, acc1, 0, 0, 0);
  }

  // per-wave denominator for query l15: sum the 4 key-groups (g) in-wave
  denom += __shfl_xor(denom, 16);
  denom += __shfl_xor(denom, 32);

  // stash per-wave partials
#pragma unroll
  for (int r = 0; r < 4; ++r) {
    ylds[w][4 * g + r][l15]      = acc0[r];
    ylds[w][4 * g + r][16 + l15] = acc1[r];
  }
  if (g == 0) dlds[w][l15] = denom;
  __syncthreads();

  // combine across wk waves + normalize; coalesced f32 writes (M-view rows)
  const int c  = tid & 31;
  const int qq = (tid >> 5) & 15;
#pragma unroll
  for (int wqi = 0; wqi < 2; ++wqi) {
    float y = 0.f, d = 0.f;
#pragma unroll
    for (int k2 = 0; k2 < 4; ++k2) {
      y += ylds[wqi * 4 + k2][qq][c];
      d += dlds[wqi * 4 + k2][qq];
    }
    Y[b * PB + (q_blk * 32 + wqi * 16 + qq) * 32 + c] = y / d;
  }
}

// ---------------------------------------------------------------------------
// Kernel 4: final 1x1 conv (reads Y flat as [o][s] view). grid (25, B) x 256.
// ---------------------------------------------------------------------------
__global__ __launch_bounds__(256) void conv_out_kernel(
    const float* __restrict__ y, const float* __restrict__ wy,
    const float* __restrict__ by, float* __restrict__ z) {
  const int b = blockIdx.y;
  const int s = blockIdx.x * 256 + threadIdx.x;

  __shared__ float wsm[CIN * COUT];   // 8 KiB, w_y is [CIN][COUT] row-major
  for (int i = threadIdx.x; i < CIN * COUT; i += 256) wsm[i] = wy[i];
  __syncthreads();

  float yr[COUT];
#pragma unroll
  for (int o = 0; o < COUT; ++o) yr[o] = y[(size_t)b * PB + o * HW + s];

  for (int i = 0; i < CIN; ++i) {
    const float4* wr = (const float4*)&wsm[i * COUT];
    float acc = 0.f;
#pragma unroll
    for (int q = 0; q < COUT / 4; ++q) {
      float4 wv = wr[q];
      acc += wv.x * yr[4*q] + wv.y * yr[4*q+1] + wv.z * yr[4*q+2] + wv.w * yr[4*q+3];
    }
    z[(size_t)b * XB + i * HW + s] = acc + by[i];
  }
}

// ---------------------------------------------------------------------------
extern "C" void kernel_launch(void* const* d_in, const int* in_sizes, int n_in,
                              void* d_out, int out_size, void* d_ws, size_t ws_size,
                              hipStream_t stream) {
  const float* x       = (const float*)d_in[0];
  const float* w_g     = (const float*)d_in[1];
  const float* b_g     = (const float*)d_in[2];
  const float* w_phi   = (const float*)d_in[3];
  const float* b_phi   = (const float*)d_in[4];
  const float* w_theta = (const float*)d_in[5];
  const float* b_theta = (const float*)d_in[6];
  const float* w_y     = (const float*)d_in[7];
  const float* b_y     = (const float*)d_in[8];
  float* z = (float*)d_out;

  char* base = (char*)d_ws;
  const size_t BF = (size_t)BATCH * PB * sizeof(ushort);  // 819200 B
  ushort* T_hi  = (ushort*)(base);
  ushort* T_lo  = (ushort*)(base + 1 * BF);
  ushort* P_hi  = (ushort*)(base + 2 * BF);
  ushort* P_lo  = (ushort*)(base + 3 * BF);
  ushort* G_hi  = (ushort*)(base + 4 * BF);
  ushort* G_lo  = (ushort*)(base + 5 * BF);
  ushort* Gt_hi = (ushort*)(base + 6 * BF);
  ushort* Gt_lo = (ushort*)(base + 7 * BF);
  float*  Y     = (float*)(base + 8 * BF);                // 1.64 MB

  conv3_kernel<<<dim3(25, 3, BATCH), 256, 0, stream>>>(
      x, w_theta, b_theta, w_phi, b_phi, w_g, b_g,
      T_hi, T_lo, P_hi, P_lo, G_hi, G_lo);
  transpose_g_kernel<<<dim3(100, BATCH), 256, 0, stream>>>(
      G_hi, G_lo, Gt_hi, Gt_lo);
  attn_kernel<<<dim3(200, BATCH), 512, 0, stream>>>(
      T_hi, T_lo, P_hi, P_lo, Gt_hi, Gt_lo, Y);
  conv_out_kernel<<<dim3(25, BATCH), 256, 0, stream>>>(Y, w_y, b_y, z);
}